// Round 8
// baseline (402.242 us; speedup 1.0000x reference)
//
#include <hip/hip_runtime.h>

#define VOCAB   32000
#define EMBED   2048
#define RANK    16
#define NADAPT  8
#define S_TOK   16384
#define T_TOK   32     // tokens per k2 block
#define GRP     4      // base-gather prefetch depth (float4 rows in flight)
#define EPT     4      // e-elements per thread (one float4)
// block covers 256*4 = 1024 e  -> 2 e-chunks per 2048-row

// ---------------- Kernel 1: bucket tokens by adapter ----------------
// d_ws layout: [0..7] int counters, [8 ..] int bucket[8][S_TOK]
__global__ __launch_bounds__(256)
void bucket_kernel(const int* __restrict__ input_ids,
                   const int* __restrict__ adapter_ids,
                   int* __restrict__ counters,
                   int* __restrict__ bucket)
{
    const int tid = threadIdx.x;
    const int t   = blockIdx.x * 256 + tid;
    int id = input_ids[t];
    if (id > VOCAB - 1) id = 0;
    const int ad = adapter_ids[t];

    __shared__ int hist[NADAPT];
    __shared__ int base[NADAPT];
    if (tid < NADAPT) hist[tid] = 0;
    __syncthreads();
    const int rank = atomicAdd(&hist[ad], 1);      // LDS atomic: local rank
    __syncthreads();
    if (tid < NADAPT)
        base[tid] = atomicAdd(&counters[tid], hist[tid]);  // global base
    __syncthreads();
    // pack: id < 2^15, t < 2^14  ->  (id<<16)|t fits in positive int32
    bucket[ad * S_TOK + base[ad] + rank] = (id << 16) | t;
}

// ---------------- Kernel 2: per-adapter fused embed + LoRA, 16B/lane ----------------
__global__ __launch_bounds__(256, 4)   // cap VGPR at 128 -> 4 waves/SIMD
void lora_embed_kernel(const int* __restrict__ counters,
                       const int* __restrict__ bucket,
                       const float* __restrict__ weight,
                       const float* __restrict__ embA,
                       const float* __restrict__ embB,
                       float* __restrict__ out)
{
    const int tid    = threadIdx.x;
    const int echunk = blockIdx.x & 1;                 // 2 e-chunks of 1024
    const int chunk  = (blockIdx.x >> 1) & 511;        // up to 512 token chunks
    const int ad     = blockIdx.x >> 10;               // 8 adapters

    const int n     = counters[ad];
    const int start = chunk * T_TOK;
    if (start >= n) return;                 // over-dispatched block: no work
    const int cnt = min(T_TOK, n - start);
    const int e0  = echunk * 1024 + tid * EPT;         // first of 4 consecutive e

    __shared__ int   pk_s[T_TOK];
    __shared__ float a_s[T_TOK][RANK];

    if (tid < cnt) pk_s[tid] = bucket[ad * S_TOK + start + tid];
    __syncthreads();

    // stage LoRA-A vectors: cnt x 16 floats (<= 2 KiB)
    for (int j = tid; j < cnt * RANK; j += 256) {
        const int i = j >> 4, r = j & 15;
        const int id = ((unsigned)pk_s[i]) >> 16;
        a_s[i][r] = embA[((long)ad * VOCAB + id) * RANK + r];
    }

    // B slices for this thread's 4 e-values: 16 float4 = 64 VGPRs,
    // 256 contiguous bytes per thread (fully coalesced across the wave)
    float4 b[EPT][4];
    {
        const float4* B4 = (const float4*)(embB + ((long)ad * EMBED + e0) * RANK);
        #pragma unroll
        for (int je = 0; je < EPT; ++je)
            #pragma unroll
            for (int c = 0; c < 4; ++c)
                b[je][c] = B4[je * 4 + c];
    }
    __syncthreads();

    int g = 0;
    for (; g + GRP <= cnt; g += GRP) {
        float4 basev[GRP];
        int    idxg[GRP];
        #pragma unroll
        for (int u = 0; u < GRP; ++u) {
            const int pk = __builtin_amdgcn_readfirstlane(pk_s[g + u]);   // SGPR
            idxg[u] = pk & 0xFFFF;
            const int id = ((unsigned)pk) >> 16;
            basev[u] = *(const float4*)&weight[(long)id * EMBED + e0];    // dwordx4 gather
        }
        #pragma unroll
        for (int u = 0; u < GRP; ++u) {
            const int i = g + u;
            const float4 a0 = *(const float4*)&a_s[i][0];
            const float4 a1 = *(const float4*)&a_s[i][4];
            const float4 a2 = *(const float4*)&a_s[i][8];
            const float4 a3 = *(const float4*)&a_s[i][12];
            float4 r = basev[u];
            float* rp = &r.x;
            #pragma unroll
            for (int je = 0; je < EPT; ++je) {   // 4 independent 16-FMA chains
                float s = rp[je];
                s = fmaf(a0.x, b[je][0].x, s); s = fmaf(a0.y, b[je][0].y, s);
                s = fmaf(a0.z, b[je][0].z, s); s = fmaf(a0.w, b[je][0].w, s);
                s = fmaf(a1.x, b[je][1].x, s); s = fmaf(a1.y, b[je][1].y, s);
                s = fmaf(a1.z, b[je][1].z, s); s = fmaf(a1.w, b[je][1].w, s);
                s = fmaf(a2.x, b[je][2].x, s); s = fmaf(a2.y, b[je][2].y, s);
                s = fmaf(a2.z, b[je][2].z, s); s = fmaf(a2.w, b[je][2].w, s);
                s = fmaf(a3.x, b[je][3].x, s); s = fmaf(a3.y, b[je][3].y, s);
                s = fmaf(a3.z, b[je][3].z, s); s = fmaf(a3.w, b[je][3].w, s);
                rp[je] = s;
            }
            *(float4*)&out[(long)idxg[u] * EMBED + e0] = r;               // dwordx4 store
        }
    }
    // tail
    for (; g < cnt; ++g) {
        const int pk  = __builtin_amdgcn_readfirstlane(pk_s[g]);
        const int idx = pk & 0xFFFF;
        const int id  = ((unsigned)pk) >> 16;
        float4 r = *(const float4*)&weight[(long)id * EMBED + e0];
        const float4 a0 = *(const float4*)&a_s[g][0];
        const float4 a1 = *(const float4*)&a_s[g][4];
        const float4 a2 = *(const float4*)&a_s[g][8];
        const float4 a3 = *(const float4*)&a_s[g][12];
        float* rp = &r.x;
        #pragma unroll
        for (int je = 0; je < EPT; ++je) {
            float s = rp[je];
            s = fmaf(a0.x, b[je][0].x, s); s = fmaf(a0.y, b[je][0].y, s);
            s = fmaf(a0.z, b[je][0].z, s); s = fmaf(a0.w, b[je][0].w, s);
            s = fmaf(a1.x, b[je][1].x, s); s = fmaf(a1.y, b[je][1].y, s);
            s = fmaf(a1.z, b[je][1].z, s); s = fmaf(a1.w, b[je][1].w, s);
            s = fmaf(a2.x, b[je][2].x, s); s = fmaf(a2.y, b[je][2].y, s);
            s = fmaf(a2.z, b[je][2].z, s); s = fmaf(a2.w, b[je][2].w, s);
            s = fmaf(a3.x, b[je][3].x, s); s = fmaf(a3.y, b[je][3].y, s);
            s = fmaf(a3.z, b[je][3].z, s); s = fmaf(a3.w, b[je][3].w, s);
            rp[je] = s;
        }
        *(float4*)&out[(long)idx * EMBED + e0] = r;
    }
}

extern "C" void kernel_launch(void* const* d_in, const int* in_sizes, int n_in,
                              void* d_out, int out_size, void* d_ws, size_t ws_size,
                              hipStream_t stream) {
    const int*   input_ids   = (const int*)d_in[0];
    const int*   adapter_ids = (const int*)d_in[1];
    const float* weight      = (const float*)d_in[2];
    const float* embA        = (const float*)d_in[3];
    const float* embB        = (const float*)d_in[4];
    float*       out         = (float*)d_out;

    int* counters = (int*)d_ws;
    int* bucket   = counters + NADAPT;

    // zero the 8 bucket counters (ws is re-poisoned to 0xAA each call)
    hipMemsetAsync(counters, 0, NADAPT * sizeof(int), stream);

    hipLaunchKernelGGL(bucket_kernel, dim3(S_TOK / 256), dim3(256), 0, stream,
                       input_ids, adapter_ids, counters, bucket);

    // grid: 8 adapters x 512 token-chunks (worst case) x 2 e-chunks = 8192 blocks
    hipLaunchKernelGGL(lora_embed_kernel,
                       dim3(NADAPT * (S_TOK / T_TOK) * 2), dim3(256),
                       0, stream,
                       counters, bucket, weight, embA, embB, out);
}